// Round 6
// baseline (384.168 us; speedup 1.0000x reference)
//
#include <hip/hip_runtime.h>
#include <cstdint>
#include <cstddef>

// Problem constants (B=8, S=2048, D=1024)
#define BATCH 8
#define SEQ   2048
#define DM    1024

typedef _Float16 half8 __attribute__((ext_vector_type(8)));
typedef _Float16 half4v __attribute__((ext_vector_type(4)));
typedef float floatx4 __attribute__((ext_vector_type(4)));
typedef float float4v __attribute__((ext_vector_type(4)));

#define GLOBAL_AS __attribute__((address_space(1)))
#define LDS_AS    __attribute__((address_space(3)))

// Async global->LDS, 16B per lane. LDS dest = wave-uniform base + lane*16.
__device__ __forceinline__ void gl_lds16(const _Float16* g, _Float16* l) {
    __builtin_amdgcn_global_load_lds((const GLOBAL_AS void*)g, (LDS_AS void*)l, 16, 0, 0);
}

// ---------------------------------------------------------------------------
// Stage one half-tile: 128 rows x 64 cols (f16), chunk-XOR swizzled
// (slot s of row r holds global chunk s ^ (r&7)). 512 thr, 2 loads each.
// ---------------------------------------------------------------------------
__device__ __forceinline__ void stage128(const _Float16* __restrict__ g, int ld, int k0,
                                         _Float16* l, int wave, int lane) {
    const int rw = wave * 8 + (lane >> 3);
    const int sl = lane & 7;
    #pragma unroll
    for (int i = 0; i < 2; i++) {
        const int r = i * 64 + rw;
        gl_lds16(g + (size_t)r * ld + k0 + ((sl ^ (r & 7)) << 3),
                 l + ((i * 64 + wave * 8) << 6));
    }
}

#define SCHED __builtin_amdgcn_sched_barrier(0)
#define BAR   __builtin_amdgcn_s_barrier()
#define WAIT_VM0    asm volatile("s_waitcnt vmcnt(0)" ::: "memory")
#define WAIT_LGKM12 asm volatile("s_waitcnt lgkmcnt(12)" ::: "memory")
#define WAIT_LGKM6  asm volatile("s_waitcnt lgkmcnt(6)" ::: "memory")
#define WAIT_LGKM4  asm volatile("s_waitcnt lgkmcnt(4)" ::: "memory")
#define WAIT_LGKM0  asm volatile("s_waitcnt lgkmcnt(0)" ::: "memory")

// Fragment sub-batch reads (16x16x32 pattern, PROVEN conflict-free: 0
// SQ_LDS_BANK_CONFLICT measured R2/R3/R5). Batch sizes 6/2/4 pair with the
// counted-lgkm ledger below — each macro = exactly that many ds_read_b128.
#define RD_A03(AV, BUF, SL)                                                   \
    _Pragma("unroll")                                                         \
    for (int i_ = 0; i_ < 4; i_++)                                            \
        AV[i_] = *(const half8*)&SA[BUF][aoff + i_ * 1024 + (SL)];
#define RD_A47(AV, BUF, SL)                                                   \
    _Pragma("unroll")                                                         \
    for (int i_ = 0; i_ < 4; i_++)                                            \
        AV[4 + i_] = *(const half8*)&SA[BUF][aoff + 8192 + i_ * 1024 + (SL)];
#define RD_B01(BV, BUF, SL)                                                   \
    _Pragma("unroll")                                                         \
    for (int j_ = 0; j_ < 2; j_++)                                            \
        BV[j_] = *(const half8*)&SB[BUF][boff + j_ * 4096 + (SL)];
#define RD_B23(BV, BUF, SL)                                                   \
    _Pragma("unroll")                                                         \
    for (int j_ = 0; j_ < 2; j_++)                                            \
        BV[2 + j_] = *(const half8*)&SB[BUF][boff + 8192 + j_ * 4096 + (SL)];

// MFMA group over acc[I0..I0+IN) x [J0..J0+JN), setprio-wrapped.
#define MM_G(AV, BV, I0, IN, J0, JN)                                          \
    __builtin_amdgcn_s_setprio(1);                                            \
    _Pragma("unroll")                                                         \
    for (int i_ = (I0); i_ < (I0) + (IN); i_++)                               \
        _Pragma("unroll")                                                     \
        for (int j_ = (J0); j_ < (J0) + (JN); j_++)                           \
            acc[i_][j_] = __builtin_amdgcn_mfma_f32_16x16x32_f16(             \
                AV[i_], BV[j_], acc[i_][j_], 0, 0, 0);                        \
    __builtin_amdgcn_s_setprio(0);

// ---------------------------------------------------------------------------
// 256x256 C = A.B^T, fine-grained interleaved engine, BK=64, 512 thr, 8 waves.
// R6: R5's loop (1 barrier/kt, conflict-free frags, same accumulation order)
// with ~6-read / 8-MFMA interleave + exact counted-lgkm ledger, so each MFMA
// group starts as soon as ITS operands drain (R5's big bursts serialized the
// LDS and MFMA pipes: measured kt 5550 cyc = 2484 MFMA + ~3050 LDS = SUM).
// Per kt (entering with 12 reads in flight = next set0):
//   issue R4(6: a1[0..3],b1[0..1])        -> lgkm(12) [set0 a03/b01 done]
//   G1: 8 MFMA (a0[0..3] x b0[0..1])
//   issue R5(2: b1[2..3])                 -> lgkm(12) [b0[2..3] done]
//   G2: 8 MFMA (a0[0..3] x b0[2..3])
//   issue R6(4: a1[4..7])                 -> lgkm(12) [a0[4..7] done]
//   G3: 16 MFMA (a0[4..7] x b0[0..3])
//   lgkm(6) [R4 done] -> G4 ; lgkm(4) [R5 done] -> G5 ; lgkm(0) [R6 done]
//   vm(0); BAR; issue next set0 (12 reads, runs under G6); G6: 16 MFMA.
// Stage of kt+1 (4 half-tiles, 8 gl_lds) spread 1 per group slot; vm(0) gate
// at tail has ~a full kt of lead. Restage safety: all reads of a buffer
// drain at lgkm(0) BEFORE the barrier preceding its restage (same as R5).
// ---------------------------------------------------------------------------
__device__ __forceinline__ void gemm256_rr(
    const _Float16* __restrict__ A, const _Float16* __restrict__ B,
    int lda, int ldb, int nkt,
    _Float16 (&SA)[2][16384], _Float16 (&SB)[2][16384],
    floatx4 (&acc)[8][4])
{
    const int t = threadIdx.x;
    const int wave = t >> 6, lane = t & 63;
    const int l15 = lane & 15, kq = lane >> 4;
    const int wm = wave >> 2, wn = wave & 3;

    const int aoff = (wm * 64 + l15) << 6;          // A frag row base (elts)
    const int boff = (wn * 16 + l15) << 6;          // B frag row base
    const int sl0 = ((kq ^ (l15 & 7)) << 3);        // k-half 0 swizzled slot
    const int sl1 = (((4 + kq) ^ (l15 & 7)) << 3);  // k-half 1

    const _Float16* A128 = A + (size_t)128 * lda;
    const _Float16* B128 = B + (size_t)128 * ldb;

    half8 a0[8], b0[4], a1[8], b1[4];

    // Prologue: stage K-tile 0 into buf0; preload set0 (12 reads in flight).
    stage128(A,    lda, 0, &SA[0][0],    wave, lane);
    stage128(A128, lda, 0, &SA[0][8192], wave, lane);
    stage128(B,    ldb, 0, &SB[0][0],    wave, lane);
    stage128(B128, ldb, 0, &SB[0][8192], wave, lane);
    WAIT_VM0; BAR; SCHED;
    RD_A03(a0, 0, sl0); RD_B01(b0, 0, sl0);
    RD_B23(b0, 0, sl0); RD_A47(a0, 0, sl0);

    for (int kt = 0; kt < nkt; ++kt) {
        const int bs = kt & 1;
        const bool more = (kt + 1) < nkt;
        const int k1 = (kt + 1) * 64;

        if (more) stage128(A, lda, k1, &SA[bs ^ 1][0], wave, lane);
        RD_A03(a1, bs, sl1); RD_B01(b1, bs, sl1);     // R4: +6
        WAIT_LGKM12; SCHED;
        MM_G(a0, b0, 0, 4, 0, 2);                     // G1
        if (more) stage128(A128, lda, k1, &SA[bs ^ 1][8192], wave, lane);
        RD_B23(b1, bs, sl1);                          // R5: +2
        WAIT_LGKM12; SCHED;
        MM_G(a0, b0, 0, 4, 2, 2);                     // G2
        if (more) stage128(B, ldb, k1, &SB[bs ^ 1][0], wave, lane);
        RD_A47(a1, bs, sl1);                          // R6: +4
        WAIT_LGKM12; SCHED;
        MM_G(a0, b0, 4, 4, 0, 4);                     // G3 (16)
        if (more) stage128(B128, ldb, k1, &SB[bs ^ 1][8192], wave, lane);
        WAIT_LGKM6; SCHED;
        MM_G(a1, b1, 0, 4, 0, 2);                     // G4
        WAIT_LGKM4; SCHED;
        MM_G(a1, b1, 0, 4, 2, 2);                     // G5
        WAIT_LGKM0; SCHED;
        if (more) {
            WAIT_VM0;                                 // kt+1 tile landed
            BAR; SCHED;
            RD_A03(a0, bs ^ 1, sl0); RD_B01(b0, bs ^ 1, sl0);
            RD_B23(b0, bs ^ 1, sl0); RD_A47(a0, bs ^ 1, sl0);  // next set0
        }
        MM_G(a1, b1, 4, 4, 0, 4);                     // G6 (16), covers reads
    }
}

// ---------------------------------------------------------------------------
// Kernel 1: fp32 -> fp16, vectorized float4 -> half4.  (unchanged)
// ---------------------------------------------------------------------------
__global__ __launch_bounds__(256) void convert_inputs(
    const float* __restrict__ src,
    const float* __restrict__ Wk, const float* __restrict__ Wv, const float* __restrict__ Wq,
    _Float16* __restrict__ Xh, _Float16* __restrict__ Wh)
{
    const int gid = blockIdx.x * 256 + threadIdx.x;
    const int gs  = gridDim.x * 256;
    const int nX4 = BATCH * SEQ * DM / 4;
    const int nW4 = DM * DM / 4;
    const float4v* s4  = (const float4v*)src;
    const float4v* wk4 = (const float4v*)Wk;
    const float4v* wv4 = (const float4v*)Wv;
    const float4v* wq4 = (const float4v*)Wq;
    half4v* x4 = (half4v*)Xh;
    half4v* w4 = (half4v*)Wh;
    for (int i = gid; i < nX4; i += gs) {
        float4v v = s4[i];
        half4v h;
        #pragma unroll
        for (int e = 0; e < 4; e++) h[e] = (_Float16)v[e];
        x4[i] = h;
    }
    for (int i = gid; i < nW4; i += gs) {
        float4v a = wk4[i], b = wv4[i], c = wq4[i];
        half4v ha, hb, hc;
        #pragma unroll
        for (int e = 0; e < 4; e++) { ha[e] = (_Float16)a[e]; hb[e] = (_Float16)b[e]; hc[e] = (_Float16)c[e]; }
        w4[i]           = ha;
        w4[nW4 + i]     = hb;
        w4[2 * nW4 + i] = hc;
    }
}

// ---------------------------------------------------------------------------
// Kernel 2: QKV projection, 768 blocks x 512 thr, 256^2 tiles, XCD-bijective.
//   z=0: K[s][d]  = X.Wk^T + bk
//   z=1: Vt[d][s] = Wv.X^T + bv[d]
//   z=2: Q[s][d]  = X.Wq^T + bq
// C/D map (16x16x32): col = lane&15, row = (lane>>4)*4 + reg.
// ---------------------------------------------------------------------------
__global__ __launch_bounds__(512, 2) void qkv_gemm(
    const _Float16* __restrict__ Xh, const _Float16* __restrict__ Wh,
    const float* __restrict__ bk, const float* __restrict__ bv, const float* __restrict__ bq,
    _Float16* __restrict__ Kh, _Float16* __restrict__ Vt, _Float16* __restrict__ Qh)
{
    __shared__ __align__(16) _Float16 SA[2][16384];
    __shared__ __align__(16) _Float16 SB[2][16384];
    const int L = blockIdx.x;                 // 768 = 8 XCD x 96
    const int lid = (L & 7) * 96 + (L >> 3);
    const int z = lid >> 8;
    const int r = lid & 255;
    int by, bx;
    const _Float16 *A, *B;
    if (z == 1) {
        by = r & 3; bx = r >> 2;              // consecutive lids share X panel
        A = Wh + (size_t)DM * DM + (size_t)by * 256 * DM;
        B = Xh + (size_t)bx * 256 * DM;
    } else {
        by = r >> 2; bx = r & 3;              // consecutive lids share X panel
        A = Xh + (size_t)by * 256 * DM;
        B = Wh + (z ? (size_t)2 * DM * DM : (size_t)0) + (size_t)bx * 256 * DM;
    }
    floatx4 acc[8][4] = {};
    gemm256_rr(A, B, DM, DM, 16, SA, SB, acc);

    const int t = threadIdx.x, wave = t >> 6, lane = t & 63;
    const int l15 = lane & 15, kq = lane >> 4;
    const int wm = wave >> 2, wn = wave & 3;
    if (z == 1) {
        #pragma unroll
        for (int i = 0; i < 8; i++)
            #pragma unroll
            for (int j = 0; j < 4; j++)
                #pragma unroll
                for (int rr = 0; rr < 4; rr++) {
                    const int d  = by * 256 + wm * 64 + (i & 3) * 16 + (i >> 2) * 128 + kq * 4 + rr;
                    const int sg = bx * 256 + wn * 16 + (j & 1) * 64 + (j >> 1) * 128 + l15;
                    const int b = sg >> 11, s = sg & (SEQ - 1);
                    Vt[((size_t)b * DM + d) * SEQ + s] = (_Float16)(acc[i][j][rr] + bv[d]);
                }
    } else {
        const float* bias = z ? bq : bk;
        _Float16* outp    = z ? Qh : Kh;
        #pragma unroll
        for (int i = 0; i < 8; i++)
            #pragma unroll
            for (int j = 0; j < 4; j++)
                #pragma unroll
                for (int rr = 0; rr < 4; rr++) {
                    const int row = by * 256 + wm * 64 + (i & 3) * 16 + (i >> 2) * 128 + kq * 4 + rr;
                    const int col = bx * 256 + wn * 16 + (j & 1) * 64 + (j >> 1) * 128 + l15;
                    outp[(size_t)row * DM + col] = (_Float16)(acc[i][j][rr] + bias[col]);
                }
    }
}

// ---------------------------------------------------------------------------
// Kernel 3: scores (fp16) = Q.K^T * (1/32) + pad[b][k]; lower-tri 256-tiles.
// 288 blocks = 8 batches x 36 tri-tiles; XCD x owns batch x.
// ---------------------------------------------------------------------------
__global__ __launch_bounds__(512, 2) void scores_gemm(
    const _Float16* __restrict__ Qh, const _Float16* __restrict__ Kh,
    const float* __restrict__ pad, _Float16* __restrict__ Sc)
{
    __shared__ __align__(16) _Float16 SA[2][16384];
    __shared__ __align__(16) _Float16 SB[2][16384];
    const int L = blockIdx.x;                 // 288 = 8 XCD x 36
    const int lid = (L & 7) * 36 + (L >> 3);
    const int b = lid / 36, tri = lid - b * 36;
    int by = 0;
    #pragma unroll
    for (int u = 1; u <= 7; u++) if (tri >= (u * (u + 1)) / 2) by = u;
    const int bx = tri - (by * (by + 1)) / 2;

    const _Float16* A = Qh + ((size_t)b * SEQ + by * 256) * DM;
    const _Float16* B = Kh + ((size_t)b * SEQ + bx * 256) * DM;
    floatx4 acc[8][4] = {};
    gemm256_rr(A, B, DM, DM, 16, SA, SB, acc);

    const int t = threadIdx.x, wave = t >> 6, lane = t & 63;
    const int l15 = lane & 15, kq = lane >> 4;
    const int wm = wave >> 2, wn = wave & 3;
    #pragma unroll
    for (int i = 0; i < 8; i++)
        #pragma unroll
        for (int j = 0; j < 4; j++)
            #pragma unroll
            for (int rr = 0; rr < 4; rr++) {
                const int row = by * 256 + wm * 64 + (i & 3) * 16 + (i >> 2) * 128 + kq * 4 + rr;
                const int col = bx * 256 + wn * 16 + (j & 1) * 64 + (j >> 1) * 128 + l15;
                Sc[((size_t)b * SEQ + row) * SEQ + col] =
                    (_Float16)(acc[i][j][rr] * 0.03125f + pad[b * SEQ + col]);
            }
}

// ---------------------------------------------------------------------------
// Kernel 4: in-place row softmax over k in [0,q]; zeros for k in (q, kmaxr).
// kmaxr 256-granular (pv reads 256-wide tiles).
// ---------------------------------------------------------------------------
__global__ __launch_bounds__(256) void softmax_rows(_Float16* __restrict__ Sc)
{
    const int bid = blockIdx.x;
    const int b = bid >> 11, q = bid & (SEQ - 1);
    _Float16* row = Sc + ((size_t)b * SEQ + q) * SEQ;
    const int n = q + 1;
    const int kmaxr = ((q >> 8) + 1) << 8;
    const int t = threadIdx.x;
    const int c0 = t * 8;
    const bool active = (c0 < kmaxr);
    __shared__ float red[4];

    half8 v = {};
    if (active) v = *(const half8*)(row + c0);
    float f[8];
    float m = -3.0e38f;
    #pragma unroll
    for (int e = 0; e < 8; e++) {
        f[e] = (active && (c0 + e < n)) ? (float)v[e] : -3.0e38f;
        m = fmaxf(m, f[e]);
    }
    #pragma unroll
    for (int o = 32; o > 0; o >>= 1) m = fmaxf(m, __shfl_down(m, o));
    if ((t & 63) == 0) red[t >> 6] = m;
    __syncthreads();
    m = fmaxf(fmaxf(red[0], red[1]), fmaxf(red[2], red[3]));

    float ex[8], s = 0.f;
    #pragma unroll
    for (int e = 0; e < 8; e++) {
        ex[e] = (f[e] > -1.0e38f) ? __expf(f[e] - m) : 0.f;
        s += ex[e];
    }
    #pragma unroll
    for (int o = 32; o > 0; o >>= 1) s += __shfl_down(s, o);
    __syncthreads();
    if ((t & 63) == 0) red[t >> 6] = s;
    __syncthreads();
    s = red[0] + red[1] + red[2] + red[3];

    if (active) {
        const float inv = 1.0f / s;
        half8 o8;
        #pragma unroll
        for (int e = 0; e < 8; e++) o8[e] = (_Float16)(ex[e] * inv);
        *(half8*)(row + c0) = o8;
    }
}

// ---------------------------------------------------------------------------
// Kernel 5: O[q][d] = sum_k P[q][k] * Vt[d][k]; K-loop stops after q-tile.
// 256 blocks, 1/CU; XCD x owns batch x; longest tiles (by=7) first.
// ---------------------------------------------------------------------------
__global__ __launch_bounds__(512, 2) void pv_gemm(
    const _Float16* __restrict__ P, const _Float16* __restrict__ Vt,
    float* __restrict__ out)
{
    __shared__ __align__(16) _Float16 SA[2][16384];
    __shared__ __align__(16) _Float16 SB[2][16384];
    const int L = blockIdx.x;                 // 256 = 8 XCD x 32
    const int lid = (L & 7) * 32 + (L >> 3);
    const int b = lid >> 5, r = lid & 31;
    const int by = 7 - (r >> 2);              // long tiles first
    const int bx = r & 3;

    const _Float16* A = P  + ((size_t)b * SEQ + by * 256) * SEQ;
    const _Float16* B = Vt + ((size_t)b * DM  + bx * 256) * SEQ;
    const int nkt = (by + 1) * 4;             // K = (by+1)*256, P zero beyond
    floatx4 acc[8][4] = {};
    gemm256_rr(A, B, SEQ, SEQ, nkt, SA, SB, acc);

    const int t = threadIdx.x, wave = t >> 6, lane = t & 63;
    const int l15 = lane & 15, kq = lane >> 4;
    const int wm = wave >> 2, wn = wave & 3;
    #pragma unroll
    for (int i = 0; i < 8; i++)
        #pragma unroll
        for (int j = 0; j < 4; j++)
            #pragma unroll
            for (int rr = 0; rr < 4; rr++) {
                const int row = by * 256 + wm * 64 + (i & 3) * 16 + (i >> 2) * 128 + kq * 4 + rr;
                const int col = bx * 256 + wn * 16 + (j & 1) * 64 + (j >> 1) * 128 + l15;
                out[((size_t)b * SEQ + row) * DM + col] = acc[i][j][rr];
            }
}

// ---------------------------------------------------------------------------
// Workspace layout (bytes) — total 174,063,616:
//   Wh @ 0         :  6,291,456  (3x1024x1024 fp16)
//   Qh @ 6291456   : 33,554,432
//   Kh @ 39845888  : 33,554,432
//   Vt @ 73400320  : 33,554,432  ([B][D][S] fp16, written directly by qkv z=1)
//   Sc @ 106954752 : 67,108,864  (8x2048x2048 fp16; softmax in-place -> P)
// Xh (fp16 src, 33.5 MB) lives in d_out; dead before pv_gemm writes out.
// ---------------------------------------------------------------------------
extern "C" void kernel_launch(void* const* d_in, const int* in_sizes, int n_in,
                              void* d_out, int out_size, void* d_ws, size_t ws_size,
                              hipStream_t stream) {
    const float* src = (const float*)d_in[0];
    const float* pad = (const float*)d_in[1];
    // d_in[2] = causal mask, handled analytically
    const float* Wk = (const float*)d_in[3];
    const float* bk = (const float*)d_in[4];
    const float* Wv = (const float*)d_in[5];
    const float* bv = (const float*)d_in[6];
    const float* Wq = (const float*)d_in[7];
    const float* bq = (const float*)d_in[8];
    float* out = (float*)d_out;

    char* ws = (char*)d_ws;
    _Float16* Wh = (_Float16*)(ws);
    _Float16* Qh = (_Float16*)(ws + 6291456);
    _Float16* Kh = (_Float16*)(ws + 39845888);
    _Float16* Vt = (_Float16*)(ws + 73400320);
    _Float16* Sc = (_Float16*)(ws + 106954752);
    _Float16* Xh = (_Float16*)d_out;  // scratch inside out buffer

    convert_inputs<<<2048, 256, 0, stream>>>(src, Wk, Wv, Wq, Xh, Wh);
    qkv_gemm<<<768, 512, 0, stream>>>(Xh, Wh, bk, bv, bq, Kh, Vt, Qh);
    scores_gemm<<<288, 512, 0, stream>>>(Qh, Kh, pad, Sc);
    softmax_rows<<<BATCH * SEQ, 256, 0, stream>>>(Sc);
    pv_gemm<<<256, 512, 0, stream>>>(Sc, Vt, out);
}